// Round 4
// baseline (328.554 us; speedup 1.0000x reference)
//
#include <hip/hip_runtime.h>

// Problem constants
#define BI    1152   // B*N = 32*36
#define NREG  36
#define DD    2048
#define RR    512
#define KK    1024   // 2*R
#define ZROWS (BI*NREG)        // 41472
#define MBLK  288              // 8 bi, rows interleaved j*8+g
#define NBLK  128
#define ABUF  9216             // elems: 2 k16-planes x 288 rows x 16
#define BBUF  4096             // elems: 2 k16-planes x 128 rows x 16
#define BUFE  (ABUF+BBUF)      // 13312 elems = 26 KB per buffer

typedef __bf16 bf16;
typedef __bf16 bf16x8 __attribute__((ext_vector_type(8)));
typedef __bf16 bf16x4 __attribute__((ext_vector_type(4)));
typedef float  f32x4  __attribute__((ext_vector_type(4)));
typedef float  f32x16 __attribute__((ext_vector_type(16)));

__device__ __forceinline__ void gl_lds16(const void* g, void* l) {
  __builtin_amdgcn_global_load_lds(
      (const __attribute__((address_space(1))) unsigned int*)g,
      (__attribute__((address_space(3))) unsigned int*)l, 16, 0, 0);
}

// ---------------- stage 1a: mm f32 -> bf16 ----------------
__global__ void k_cvt_mm(const float4* __restrict__ in, bf16x4* __restrict__ out) {
  int i = blockIdx.x * 256 + threadIdx.x;
  float4 v = in[i];
  bf16x4 o = {(bf16)v.x, (bf16)v.y, (bf16)v.z, (bf16)v.w};
  out[i] = o;
}

// ------- stage 1b: U/V_feat f32 [2048][512] -> bf16 UT/VT [512 r][2048 k] -------
__global__ void k_transpose_uv(const float* __restrict__ U, const float* __restrict__ V,
                               bf16* __restrict__ UT, bf16* __restrict__ VT) {
  __shared__ float tile[32][33];
  const float* in = blockIdx.z ? V : U;
  bf16* out = blockIdx.z ? VT : UT;
  int tx = threadIdx.x, ty = threadIdx.y;
  int c0 = blockIdx.x * 32, r0 = blockIdx.y * 32;
#pragma unroll
  for (int k = 0; k < 4; k++)
    tile[ty + 8 * k][tx] = in[(long)(r0 + ty + 8 * k) * 512 + c0 + tx];
  __syncthreads();
#pragma unroll
  for (int k = 0; k < 4; k++)
    out[(long)(c0 + ty + 8 * k) * 2048 + r0 + tx] = (bf16)tile[tx][ty + 8 * k];
}

// ------- stage 1c: P_* f32 [512 r][2048 d] -> PT_t [kc][2048][32] bf16 -------
__global__ void k_transpose_pt(const float* __restrict__ Pc, const float* __restrict__ Pf,
                               bf16* __restrict__ out) {
  __shared__ float tile[32][33];
  const float* in = blockIdx.z ? Pf : Pc;
  int koff = blockIdx.z * 512;
  int tx = threadIdx.x, ty = threadIdx.y;
  int c0 = blockIdx.x * 32, r0 = blockIdx.y * 32;
#pragma unroll
  for (int k = 0; k < 4; k++)
    tile[ty + 8 * k][tx] = in[(long)(r0 + ty + 8 * k) * 2048 + c0 + tx];
  __syncthreads();
  int kc = (koff + r0) >> 5;
#pragma unroll
  for (int k = 0; k < 4; k++) {
    int d = c0 + ty + 8 * k;
    out[((long)kc * 2048 + d) * 32 + tx] = (bf16)tile[tx][ty + 8 * k];
  }
}

// ---------------- stage 2: uc/vc (K=4, fp32) ----------------
__global__ void k_uvcoord(const float* __restrict__ coords, const float* __restrict__ Uc,
                          const float* __restrict__ Vc, float* __restrict__ uc,
                          float* __restrict__ vc) {
  int g = blockIdx.x, t = threadIdx.x;
  float c0 = coords[g * 4 + 0], c1 = coords[g * 4 + 1];
  float c2 = coords[g * 4 + 2], c3 = coords[g * 4 + 3];
#pragma unroll
  for (int i = 0; i < 2; i++) {
    int r = t + i * 256;
    uc[g * RR + r] = c0 * Uc[r] + c1 * Uc[RR + r] + c2 * Uc[2 * RR + r] + c3 * Uc[3 * RR + r];
    vc[g * RR + r] = c0 * Vc[r] + c1 * Vc[RR + r] + c2 * Vc[2 * RR + r] + c3 * Vc[3 * RR + r];
  }
}

// ---------------- stage 3: uf/vf = mm @ U_feat / V_feat (MFMA bf16, dbuf) -------
__launch_bounds__(256)
__global__ void k_gemm_uv(const bf16* __restrict__ mmb, const bf16* __restrict__ UT,
                          const bf16* __restrict__ VT, float* __restrict__ uf,
                          float* __restrict__ vf) {
  __shared__ bf16 As[2][2048];
  __shared__ bf16 Bs[2][2048];
  const bf16* Bmat = blockIdx.z ? VT : UT;
  float* out = blockIdx.z ? vf : uf;
  int n0 = blockIdx.x * 64, m0 = blockIdx.y * 64;
  int tid = threadIdx.x, wave = tid >> 6, lane = tid & 63;

  const bf16* gA = mmb + (long)(m0 + lane) * 2048 + wave * 8;
  const bf16* gB = Bmat + (long)(n0 + lane) * 2048 + wave * 8;

  f32x4 acc[4] = {};
  gl_lds16(gA, As[0] + wave * 512);
  gl_lds16(gB, Bs[0] + wave * 512);
  for (int k0 = 0; k0 < 2048; k0 += 32) {
    int cur = (k0 >> 5) & 1;
    __syncthreads();
    if (k0 + 32 < 2048) {
      gl_lds16(gA + k0 + 32, As[cur ^ 1] + wave * 512);
      gl_lds16(gB + k0 + 32, Bs[cur ^ 1] + wave * 512);
    }
    bf16x8 bfr = *(const bf16x8*)(Bs[cur] + (lane >> 4) * 512 + (wave * 16 + (lane & 15)) * 8);
#pragma unroll
    for (int mt = 0; mt < 4; mt++) {
      bf16x8 afr = *(const bf16x8*)(As[cur] + (lane >> 4) * 512 + (mt * 16 + (lane & 15)) * 8);
      acc[mt] = __builtin_amdgcn_mfma_f32_16x16x32_bf16(afr, bfr, acc[mt], 0, 0, 0);
    }
  }
  int col = n0 + wave * 16 + (lane & 15);
#pragma unroll
  for (int mt = 0; mt < 4; mt++)
#pragma unroll
    for (int r = 0; r < 4; r++) {
      int row = m0 + mt * 16 + (lane >> 4) * 4 + r;
      out[(long)row * RR + col] = acc[mt][r];
    }
}

// ------- stage 4: z_t[kc][row'][32], row' = (bi>>3)*288 + j*8 + (bi&7) -------
__global__ void k_build_z(const float* __restrict__ uc, const float* __restrict__ vc,
                          const float* __restrict__ uf, const float* __restrict__ vf,
                          bf16* __restrict__ z) {
  __shared__ float uL[36 * 128];
  __shared__ float vL[36 * 128];
  int kq = blockIdx.x, b = blockIdx.y, tid = threadIdx.x;
  const float* usrc = (kq < 4) ? uc : uf;
  const float* vsrc = (kq < 4) ? vc : vf;
  int kb = (kq & 3) * 128;
  for (int i = tid; i < 1152; i += 256) {
    int row = i >> 5, kk = (i & 31) * 4;
    long src = (long)(b * 36 + row) * RR + kb + kk;
    *(float4*)&uL[row * 128 + kk] = *(const float4*)(usrc + src);
    *(float4*)&vL[row * 128 + kk] = *(const float4*)(vsrc + src);
  }
  __syncthreads();
  for (int c = tid; c < 41472; c += 256) {
    int kcl = c / 10368;
    int rem = c - kcl * 10368;
    int row = rem >> 3;             // 0..1295 = gl*36 + j
    int x4 = rem & 7;
    int gl = row / 36;
    int j = row - gl * 36;
    int kl = kcl * 32 + x4 * 4;
    float4 u4 = *(const float4*)&uL[gl * 128 + kl];
    float4 v4 = *(const float4*)&vL[j * 128 + kl];
    float x0 = fmaxf(u4.x * v4.x, 0.f), x1 = fmaxf(u4.y * v4.y, 0.f);
    float x2 = fmaxf(u4.z * v4.z, 0.f), x3 = fmaxf(u4.w * v4.w, 0.f);
    bf16x4 o = {(bf16)x0, (bf16)x1, (bf16)x2, (bf16)x3};
    int bi = b * 36 + gl;
    long rowp = (long)(bi >> 3) * 288 + j * 8 + (bi & 7);
    *(bf16x4*)(z + ((long)(kq * 4 + kcl) * ZROWS + rowp) * 32 + x4 * 4) = o;
  }
}

// ---------------- stage 5: main fused GEMM + segmented max + residual ----------------
// mfma_32x32x16_bf16. Block 288x128, 6 waves as 3m x 2n (wave = 96r x 64c),
// acc 3x2 f32x16 (96 regs) -> 3 waves/SIMD. BK=32 staged as two k16 planes
// [row][16], double-buffered (52 KB). z rows interleaved j*8+g so each 32-row
// tile holds all 8 g's; per-bi max = register fmax + LDS partial combine.
__launch_bounds__(384, 3)
__global__ void k_main(const bf16* __restrict__ z, const bf16* __restrict__ PTt,
                       const float* __restrict__ mm, float* __restrict__ out) {
  __shared__ bf16 lds[2 * BUFE];   // 52 KB
  int bid = blockIdx.x;
  int x = bid & 7, dt = (bid >> 3) & 15, chunk = bid >> 7;
  int go = chunk * 8 + x;          // 0..143 (8-bi groups)
  int d0 = dt * NBLK;
  int tid = threadIdx.x, wave = tid / 64, lane = tid & 63;
  int l31 = lane & 31, hi = lane >> 5;     // hi = k-half selector
  int ws = wave >> 1;              // m-strip 0..2 (96 rows each)
  int nh = wave & 1;               // n-half (64 cols)

  // staging: 26 segs of 1 KB. A segs 0..17: plane s=seg/9, rowblk=seg%9.
  // B segs 18..25: plane s=(seg-18)>>2, nblk=(seg-18)&3.
  // lane -> row = rowblk*32 + (lane>>1), k-half h2 = lane&1 (8 elems).
  const bf16* gp[5];
  int lofs[5];
  long kst[5];
  int rlane = lane >> 1, h2 = lane & 1;
#pragma unroll
  for (int i = 0; i < 5; i++) {
    int s = wave + 6 * i;
    if (s < 18) {
      int sp = s / 9, rblk = s - sp * 9;
      gp[i] = z + ((long)go * 288 + rblk * 32 + rlane) * 32 + sp * 16 + h2 * 8;
      lofs[i] = s * 512;
      kst[i] = (long)ZROWS * 32;
    } else if (s < 26) {
      int sb = s - 18;
      int sp = sb >> 2, nblk = sb & 3;
      gp[i] = PTt + ((long)d0 + nblk * 32 + rlane) * 32 + sp * 16 + h2 * 8;
      lofs[i] = ABUF + sb * 512;
      kst[i] = 2048L * 32;
    }
  }

  auto stage = [&](int buf) {
#pragma unroll
    for (int i = 0; i < 5; i++) {
      int s = wave + 6 * i;
      if (s < 26) {
        gl_lds16(gp[i], lds + buf * BUFE + lofs[i]);
        gp[i] += kst[i];
      }
    }
  };

  f32x16 acc[3][2] = {};
  stage(0);
  for (int kc = 0; kc < 32; kc++) {
    __syncthreads();
    if (kc < 31) stage((kc + 1) & 1);
    const bf16* cur = lds + (kc & 1) * BUFE;
#pragma unroll
    for (int sp = 0; sp < 2; sp++) {
      bf16x8 a[3], b[2];
#pragma unroll
      for (int t = 0; t < 3; t++)
        a[t] = *(const bf16x8*)(cur + sp * 4608 + (ws * 96 + t * 32 + l31) * 16 + hi * 8);
#pragma unroll
      for (int nt = 0; nt < 2; nt++)
        b[nt] = *(const bf16x8*)(cur + ABUF + sp * 2048 + (nh * 64 + nt * 32 + l31) * 16 + hi * 8);
#pragma unroll
      for (int t = 0; t < 3; t++)
#pragma unroll
        for (int nt = 0; nt < 2; nt++)
          acc[t][nt] = __builtin_amdgcn_mfma_f32_32x32x16_bf16(a[t], b[nt], acc[t][nt], 0, 0, 0);
    }
  }

  // epilogue: C row_local = (reg&3) + 8*(reg>>2) + 4*hi + 32*t (within strip).
  // Interleaved rows: g = (reg&3) + 4*hi, j = ws*12 + t*4 + (reg>>2).
  // Per-lane max over t,rq for each slot s0=reg&3; partials -> LDS (aliases buf0,
  // dead after kc=31's barrier); combine 3 m-strips + residual.
  float* pfp = (float*)lds;        // [ws 3][g 8][col 128]
#pragma unroll
  for (int nt = 0; nt < 2; nt++) {
    int col = nh * 64 + nt * 32 + l31;
#pragma unroll
    for (int s0 = 0; s0 < 4; s0++) {
      float mx = -3.0e38f;
#pragma unroll
      for (int t = 0; t < 3; t++)
#pragma unroll
        for (int rq = 0; rq < 4; rq++)
          mx = fmaxf(mx, acc[t][nt][rq * 4 + s0]);
      int g = s0 + 4 * hi;
      pfp[(ws * 8 + g) * 128 + col] = mx;
    }
  }
  __syncthreads();
  for (int o = tid; o < 1024; o += 384) {
    int g = o >> 7, col = o & 127;
    float v = fmaxf(fmaxf(pfp[g * 128 + col], pfp[(8 + g) * 128 + col]),
                    pfp[(16 + g) * 128 + col]);
    long oa = (long)(go * 8 + g) * DD + d0 + col;
    out[oa] = v + mm[oa];
  }
}

// ---------------- launcher ----------------
extern "C" void kernel_launch(void* const* d_in, const int* in_sizes, int n_in,
                              void* d_out, int out_size, void* d_ws, size_t ws_size,
                              hipStream_t stream) {
  const float* mm     = (const float*)d_in[0];
  const float* coords = (const float*)d_in[1];
  const float* U_feat = (const float*)d_in[2];
  const float* V_feat = (const float*)d_in[3];
  const float* P_feat = (const float*)d_in[4];
  const float* U_coord= (const float*)d_in[5];
  const float* V_coord= (const float*)d_in[6];
  const float* P_coord= (const float*)d_in[7];
  float* out = (float*)d_out;

  char* ws = (char*)d_ws;
  bf16* z   = (bf16*)(ws + 0);                 //  84,934,656 B  [kc][41472 row'][32]
  bf16* PTt = (bf16*)(ws + 84934656);          //   4,194,304 B  [kc][2048][32]
  bf16* mmb = (bf16*)(ws + 89128960);          //   4,718,592 B
  bf16* UT  = (bf16*)(ws + 93847552);          //   2,097,152 B  [512][2048]
  bf16* VT  = (bf16*)(ws + 95944704);          //   2,097,152 B
  float* uf = (float*)(ws + 98041856);         //   2,359,296 B
  float* vf = (float*)(ws + 100401152);
  float* uc = (float*)(ws + 102760448);
  float* vc = (float*)(ws + 105119744);        // end 107,479,040

  k_cvt_mm<<<dim3(2304), dim3(256), 0, stream>>>((const float4*)mm, (bf16x4*)mmb);
  k_transpose_uv<<<dim3(16, 64, 2), dim3(32, 8), 0, stream>>>(U_feat, V_feat, UT, VT);
  k_transpose_pt<<<dim3(64, 16, 2), dim3(32, 8), 0, stream>>>(P_coord, P_feat, PTt);
  k_uvcoord<<<dim3(BI), dim3(256), 0, stream>>>(coords, U_coord, V_coord, uc, vc);
  k_gemm_uv<<<dim3(8, 18, 2), dim3(256), 0, stream>>>(mmb, UT, VT, uf, vf);
  k_build_z<<<dim3(8, 32), dim3(256), 0, stream>>>(uc, vc, uf, vf, z);
  k_main<<<dim3(2304), dim3(384), 0, stream>>>(z, PTt, mm, out);
}

// Round 5
// 323.558 us; speedup vs baseline: 1.0154x; 1.0154x over previous
//
#include <hip/hip_runtime.h>

// Problem constants
#define BI    1152   // B*N = 32*36
#define NREG  36
#define DD    2048
#define RR    512
#define KK    1024   // 2*R
#define ZROWS (BI*NREG)        // 41472
#define MBLK  288              // 8 bi, rows interleaved j*8+g
#define NBLK  128
#define ABUF  (MBLK*32)        // 9216 elems (18 KB)
#define BBUF  (NBLK*32)        // 4096 elems (8 KB)
#define BUFE  (ABUF+BBUF)      // 13312 elems = 26 KB per buffer

typedef __bf16 bf16;
typedef __bf16 bf16x8 __attribute__((ext_vector_type(8)));
typedef __bf16 bf16x4 __attribute__((ext_vector_type(4)));
typedef float  f32x4  __attribute__((ext_vector_type(4)));

__device__ __forceinline__ void gl_lds16(const void* g, void* l) {
  __builtin_amdgcn_global_load_lds(
      (const __attribute__((address_space(1))) unsigned int*)g,
      (__attribute__((address_space(3))) unsigned int*)l, 16, 0, 0);
}

// ---------------- fused prep: cvt_mm + transpose_uv + transpose_pt + uvcoord -------
// grid: [0,2304) cvt | [2304,4352) uv-transpose | [4352,6400) pt-transpose | [6400,7552) uvcoord
__global__ void k_prep(const float* __restrict__ mm, const float* __restrict__ coords,
                       const float* __restrict__ U_feat, const float* __restrict__ V_feat,
                       const float* __restrict__ P_feat, const float* __restrict__ U_coord,
                       const float* __restrict__ V_coord, const float* __restrict__ P_coord,
                       bf16* __restrict__ mmb, bf16* __restrict__ UT, bf16* __restrict__ VT,
                       bf16* __restrict__ PTt, float* __restrict__ uc, float* __restrict__ vc) {
  __shared__ float tile[32][33];
  int bid = blockIdx.x, tid = threadIdx.x;
  if (bid < 2304) {
    int i = bid * 256 + tid;
    float4 v = ((const float4*)mm)[i];
    bf16x4 o = {(bf16)v.x, (bf16)v.y, (bf16)v.z, (bf16)v.w};
    ((bf16x4*)mmb)[i] = o;
  } else if (bid < 4352) {
    int rel = bid - 2304;
    int zz = rel >> 10, rr = rel & 1023;
    int c0 = (rr & 15) * 32, r0 = (rr >> 4) * 32;     // cols 512, rows 2048
    const float* in = zz ? V_feat : U_feat;
    bf16* outp = zz ? VT : UT;
    int tx = tid & 31, ty = tid >> 5;
#pragma unroll
    for (int k = 0; k < 4; k++)
      tile[ty + 8 * k][tx] = in[(long)(r0 + ty + 8 * k) * 512 + c0 + tx];
    __syncthreads();
#pragma unroll
    for (int k = 0; k < 4; k++)
      outp[(long)(c0 + ty + 8 * k) * 2048 + r0 + tx] = (bf16)tile[tx][ty + 8 * k];
  } else if (bid < 6400) {
    int rel = bid - 4352;
    int zz = rel >> 10, rr = rel & 1023;
    int c0 = (rr & 63) * 32, r0 = (rr >> 6) * 32;     // cols 2048, rows 512
    const float* in = zz ? P_feat : P_coord;
    int koff = zz * 512;
    int tx = tid & 31, ty = tid >> 5;
#pragma unroll
    for (int k = 0; k < 4; k++)
      tile[ty + 8 * k][tx] = in[(long)(r0 + ty + 8 * k) * 2048 + c0 + tx];
    __syncthreads();
    int kc = (koff + r0) >> 5;
#pragma unroll
    for (int k = 0; k < 4; k++) {
      int d = c0 + ty + 8 * k;
      PTt[((long)kc * 2048 + d) * 32 + tx] = (bf16)tile[tx][ty + 8 * k];
    }
  } else {
    int g = bid - 6400;
    float c0 = coords[g * 4 + 0], c1 = coords[g * 4 + 1];
    float c2 = coords[g * 4 + 2], c3 = coords[g * 4 + 3];
#pragma unroll
    for (int i = 0; i < 2; i++) {
      int r = tid + i * 256;
      uc[g * RR + r] = c0 * U_coord[r] + c1 * U_coord[RR + r] + c2 * U_coord[2 * RR + r] + c3 * U_coord[3 * RR + r];
      vc[g * RR + r] = c0 * V_coord[r] + c1 * V_coord[RR + r] + c2 * V_coord[2 * RR + r] + c3 * V_coord[3 * RR + r];
    }
  }
}

// ---------------- stage 3: uf/vf = mm @ U_feat / V_feat, 128x128 tile, dbuf -------
__launch_bounds__(256)
__global__ void k_gemm_uv(const bf16* __restrict__ mmb, const bf16* __restrict__ UT,
                          const bf16* __restrict__ VT, float* __restrict__ uf,
                          float* __restrict__ vf) {
  __shared__ bf16 lds2[2][8192];   // per buf: A 128x32 + B 128x32 (16 KB)
  const bf16* Bmat = blockIdx.z ? VT : UT;
  float* outp = blockIdx.z ? vf : uf;
  int m0 = blockIdx.x * 128, n0 = blockIdx.y * 128;
  int tid = threadIdx.x, wave = tid >> 6, lane = tid & 63;
  int l15 = lane & 15, qv = lane >> 4;
  int qp_c = qv ^ ((l15 >> 1) & 3);
  int ws2 = wave >> 1, nh2 = wave & 1;

  int qs = (lane & 3) ^ ((lane >> 3) & 3);
  int lrow = lane >> 2;
  const bf16* gp[4];
  int lofs[4];
#pragma unroll
  for (int i = 0; i < 4; i++) {
    int s = wave + 4 * i;
    if (s < 8) {
      gp[i] = mmb + (long)(m0 + s * 16 + lrow) * 2048 + qs * 8;
      lofs[i] = s * 512;
    } else {
      gp[i] = Bmat + (long)(n0 + (s - 8) * 16 + lrow) * 2048 + qs * 8;
      lofs[i] = 4096 + (s - 8) * 512;
    }
  }

  f32x4 acc[4][4] = {};
#pragma unroll
  for (int i = 0; i < 4; i++) gl_lds16(gp[i], &lds2[0][lofs[i]]);
  for (int k0 = 0; k0 < 2048; k0 += 32) {
    int cur = (k0 >> 5) & 1;
    __syncthreads();
    if (k0 + 32 < 2048) {
#pragma unroll
      for (int i = 0; i < 4; i++) gl_lds16(gp[i] + k0 + 32, &lds2[cur ^ 1][lofs[i]]);
    }
    bf16x8 a[4], b[4];
#pragma unroll
    for (int mt = 0; mt < 4; mt++)
      a[mt] = *(const bf16x8*)(&lds2[cur][0] + (ws2 * 64 + mt * 16 + l15) * 32 + qp_c * 8);
#pragma unroll
    for (int nt = 0; nt < 4; nt++)
      b[nt] = *(const bf16x8*)(&lds2[cur][4096] + (nh2 * 64 + nt * 16 + l15) * 32 + qp_c * 8);
#pragma unroll
    for (int mt = 0; mt < 4; mt++)
#pragma unroll
      for (int nt = 0; nt < 4; nt++)
        acc[mt][nt] = __builtin_amdgcn_mfma_f32_16x16x32_bf16(a[mt], b[nt], acc[mt][nt], 0, 0, 0);
  }
#pragma unroll
  for (int mt = 0; mt < 4; mt++)
#pragma unroll
    for (int nt = 0; nt < 4; nt++)
#pragma unroll
      for (int r = 0; r < 4; r++) {
        int row = m0 + ws2 * 64 + mt * 16 + qv * 4 + r;
        int col = n0 + nh2 * 64 + nt * 16 + l15;
        outp[(long)row * RR + col] = acc[mt][nt][r];
      }
}

// ------- stage 4: z_t[kc][row'][32], row' = (bi>>3)*288 + j*8 + (bi&7) -------
__global__ void k_build_z(const float* __restrict__ uc, const float* __restrict__ vc,
                          const float* __restrict__ uf, const float* __restrict__ vf,
                          bf16* __restrict__ z) {
  __shared__ float uL[36 * 128];
  __shared__ float vL[36 * 128];
  int kq = blockIdx.x, b = blockIdx.y, tid = threadIdx.x;
  const float* usrc = (kq < 4) ? uc : uf;
  const float* vsrc = (kq < 4) ? vc : vf;
  int kb = (kq & 3) * 128;
  for (int i = tid; i < 1152; i += 256) {
    int row = i >> 5, kk = (i & 31) * 4;
    long src = (long)(b * 36 + row) * RR + kb + kk;
    *(float4*)&uL[row * 128 + kk] = *(const float4*)(usrc + src);
    *(float4*)&vL[row * 128 + kk] = *(const float4*)(vsrc + src);
  }
  __syncthreads();
  for (int c = tid; c < 41472; c += 256) {
    int kcl = c / 10368;
    int rem = c - kcl * 10368;
    int row = rem >> 3;             // 0..1295 = gl*36 + j
    int x4 = rem & 7;
    int gl = row / 36;
    int j = row - gl * 36;
    int kl = kcl * 32 + x4 * 4;
    float4 u4 = *(const float4*)&uL[gl * 128 + kl];
    float4 v4 = *(const float4*)&vL[j * 128 + kl];
    float x0 = fmaxf(u4.x * v4.x, 0.f), x1 = fmaxf(u4.y * v4.y, 0.f);
    float x2 = fmaxf(u4.z * v4.z, 0.f), x3 = fmaxf(u4.w * v4.w, 0.f);
    bf16x4 o = {(bf16)x0, (bf16)x1, (bf16)x2, (bf16)x3};
    int bi = b * 36 + gl;
    long rowp = (long)(bi >> 3) * 288 + j * 8 + (bi & 7);
    *(bf16x4*)(z + ((long)(kq * 4 + kcl) * ZROWS + rowp) * 32 + x4 * 4) = o;
  }
}

// ---------------- stage 5: main fused GEMM + segmented max + residual ----------------
// 16x16x32 MFMA. Block 288x128, 6 waves as 3m x 2n (wave 96r x 64c),
// acc[6][4] f32x4 = 96 acc regs -> 3 waves/SIMD. [row][32] LDS layout with
// XOR k-quad swizzle (R3-verified conflict-free). z rows interleaved j*8+g:
// gl = (qv*4+r)&7 -> division-free segmented max.
__launch_bounds__(384, 3)
__global__ void k_main(const bf16* __restrict__ z, const bf16* __restrict__ PTt,
                       const float* __restrict__ mm, float* __restrict__ out) {
  __shared__ bf16 lds[2 * BUFE];   // 52 KB
  int bid = blockIdx.x;
  int x = bid & 7, dt = (bid >> 3) & 15, chunk = bid >> 7;
  int go = chunk * 8 + x;          // 0..143 (8-bi groups)
  int d0 = dt * NBLK;
  int tid = threadIdx.x, wave = tid / 64, lane = tid & 63;
  int l15 = lane & 15, qv = lane >> 4;
  int qp_c = qv ^ ((l15 >> 1) & 3);
  int ws = wave >> 1;              // m-strip 0..2 (96 rows)
  int nh = wave & 1;               // n-half (64 cols)

  // staging: 26 segs of 1 KB (A: 0..17 = 288 rows, B: 18..25 = 128 d-rows)
  int qs = (lane & 3) ^ ((lane >> 3) & 3);
  int lroff = (lane >> 2) * 32 + qs * 8;
  const bf16* gp[5];
  int lofs[5];
  long kst[5];
#pragma unroll
  for (int i = 0; i < 5; i++) {
    int s = wave + 6 * i;
    if (s < 18) {
      gp[i] = z + (long)go * (MBLK * 32) + s * 512 + lroff;
      lofs[i] = s * 512;
      kst[i] = (long)ZROWS * 32;
    } else if (s < 26) {
      gp[i] = PTt + (long)d0 * 32 + (s - 18) * 512 + lroff;
      lofs[i] = ABUF + (s - 18) * 512;
      kst[i] = 2048L * 32;
    }
  }

  auto stage = [&](int buf) {
#pragma unroll
    for (int i = 0; i < 5; i++) {
      int s = wave + 6 * i;
      if (s < 26) {
        gl_lds16(gp[i], lds + buf * BUFE + lofs[i]);
        gp[i] += kst[i];
      }
    }
  };

  f32x4 acc[6][4] = {};
  stage(0);
  for (int kc = 0; kc < 32; kc++) {
    __syncthreads();
    if (kc < 31) stage((kc + 1) & 1);
    const bf16* cur = lds + (kc & 1) * BUFE;
    bf16x8 a[6], b[4];
#pragma unroll
    for (int mt = 0; mt < 6; mt++)
      a[mt] = *(const bf16x8*)(cur + (ws * 96 + mt * 16 + l15) * 32 + qp_c * 8);
#pragma unroll
    for (int nt = 0; nt < 4; nt++)
      b[nt] = *(const bf16x8*)(cur + ABUF + (nh * 64 + nt * 16 + l15) * 32 + qp_c * 8);
#pragma unroll
    for (int mt = 0; mt < 6; mt++)
#pragma unroll
      for (int nt = 0; nt < 4; nt++)
        acc[mt][nt] = __builtin_amdgcn_mfma_f32_16x16x32_bf16(a[mt], b[nt], acc[mt][nt], 0, 0, 0);
  }

  // epilogue: row' = ws*96 + mt*16 + qv*4 + r; gl = (qv*4+r)&7, j = ws*12+mt*2+((qv*4+r)>>3).
  // max over mt in regs, shfl_xor(32) merges even/odd j, pf[3][8][128] merges ws strips.
  float* pf = (float*)lds;         // 12 KB, aliases buf0 (dead)
#pragma unroll
  for (int nt = 0; nt < 4; nt++) {
    int col = nh * 64 + nt * 16 + l15;
    float mx[4];
#pragma unroll
    for (int r = 0; r < 4; r++) {
      mx[r] = acc[0][nt][r];
#pragma unroll
      for (int mt = 1; mt < 6; mt++) mx[r] = fmaxf(mx[r], acc[mt][nt][r]);
      mx[r] = fmaxf(mx[r], __shfl_xor(mx[r], 32, 64));
    }
    if (qv == 0) {
#pragma unroll
      for (int r = 0; r < 4; r++) pf[(ws * 8 + r) * 128 + col] = mx[r];
    } else if (qv == 1) {
#pragma unroll
      for (int r = 0; r < 4; r++) pf[(ws * 8 + 4 + r) * 128 + col] = mx[r];
    }
  }
  __syncthreads();
  for (int o = tid; o < 1024; o += 384) {
    int gl = o >> 7, col = o & 127;
    float v = fmaxf(fmaxf(pf[gl * 128 + col], pf[(8 + gl) * 128 + col]),
                    pf[(16 + gl) * 128 + col]);
    long oa = (long)(go * 8 + gl) * DD + d0 + col;
    out[oa] = v + mm[oa];
  }
}

// ---------------- launcher ----------------
extern "C" void kernel_launch(void* const* d_in, const int* in_sizes, int n_in,
                              void* d_out, int out_size, void* d_ws, size_t ws_size,
                              hipStream_t stream) {
  const float* mm     = (const float*)d_in[0];
  const float* coords = (const float*)d_in[1];
  const float* U_feat = (const float*)d_in[2];
  const float* V_feat = (const float*)d_in[3];
  const float* P_feat = (const float*)d_in[4];
  const float* U_coord= (const float*)d_in[5];
  const float* V_coord= (const float*)d_in[6];
  const float* P_coord= (const float*)d_in[7];
  float* out = (float*)d_out;

  char* ws = (char*)d_ws;
  bf16* z   = (bf16*)(ws + 0);                 //  84,934,656 B  [kc][41472 row'][32]
  bf16* PTt = (bf16*)(ws + 84934656);          //   4,194,304 B  [kc][2048][32]
  bf16* mmb = (bf16*)(ws + 89128960);          //   4,718,592 B
  bf16* UT  = (bf16*)(ws + 93847552);          //   2,097,152 B  [512][2048]
  bf16* VT  = (bf16*)(ws + 95944704);          //   2,097,152 B
  float* uf = (float*)(ws + 98041856);         //   2,359,296 B
  float* vf = (float*)(ws + 100401152);
  float* uc = (float*)(ws + 102760448);
  float* vc = (float*)(ws + 105119744);        // end 107,479,040

  k_prep<<<dim3(7552), dim3(256), 0, stream>>>(mm, coords, U_feat, V_feat, P_feat,
                                               U_coord, V_coord, P_coord,
                                               mmb, UT, VT, PTt, uc, vc);
  k_gemm_uv<<<dim3(9, 4, 2), dim3(256), 0, stream>>>(mmb, UT, VT, uf, vf);
  k_build_z<<<dim3(8, 32), dim3(256), 0, stream>>>(uc, vc, uf, vf, z);
  k_main<<<dim3(2304), dim3(384), 0, stream>>>(z, PTt, mm, out);
}

// Round 7
// 302.072 us; speedup vs baseline: 1.0877x; 1.0711x over previous
//
#include <hip/hip_runtime.h>

// Problem constants
#define BI    1152   // B*N = 32*36
#define NREG  36
#define DD    2048
#define RR    512
#define KK    1024   // 2*R
#define ZROWS (BI*NREG)        // 41472
#define MBLK  288              // 8 bi, rows interleaved j*8+g
#define NBLK  128
#define ABUF  (MBLK*32)        // 9216 elems (18 KB)
#define BBUF  (NBLK*32)        // 4096 elems (8 KB)
#define BUFE  (ABUF+BBUF)      // 13312 elems = 26 KB per buffer

typedef __bf16 bf16;
typedef __bf16 bf16x8 __attribute__((ext_vector_type(8)));
typedef __bf16 bf16x4 __attribute__((ext_vector_type(4)));
typedef float  f32x4  __attribute__((ext_vector_type(4)));

__device__ __forceinline__ void gl_lds16(const void* g, void* l) {
  __builtin_amdgcn_global_load_lds(
      (const __attribute__((address_space(1))) unsigned int*)g,
      (__attribute__((address_space(3))) unsigned int*)l, 16, 0, 0);
}

// ---------------- fused prep: cvt_mm + transpose_uv + transpose_pt + uvcoord -------
__global__ void k_prep(const float* __restrict__ mm, const float* __restrict__ coords,
                       const float* __restrict__ U_feat, const float* __restrict__ V_feat,
                       const float* __restrict__ P_feat, const float* __restrict__ U_coord,
                       const float* __restrict__ V_coord, const float* __restrict__ P_coord,
                       bf16* __restrict__ mmb, bf16* __restrict__ UT, bf16* __restrict__ VT,
                       bf16* __restrict__ PTt, float* __restrict__ uc, float* __restrict__ vc) {
  __shared__ float tile[32][33];
  int bid = blockIdx.x, tid = threadIdx.x;
  if (bid < 2304) {
    int i = bid * 256 + tid;
    float4 v = ((const float4*)mm)[i];
    bf16x4 o = {(bf16)v.x, (bf16)v.y, (bf16)v.z, (bf16)v.w};
    ((bf16x4*)mmb)[i] = o;
  } else if (bid < 4352) {
    int rel = bid - 2304;
    int zz = rel >> 10, rr = rel & 1023;
    int c0 = (rr & 15) * 32, r0 = (rr >> 4) * 32;     // cols 512, rows 2048
    const float* in = zz ? V_feat : U_feat;
    bf16* outp = zz ? VT : UT;
    int tx = tid & 31, ty = tid >> 5;
#pragma unroll
    for (int k = 0; k < 4; k++)
      tile[ty + 8 * k][tx] = in[(long)(r0 + ty + 8 * k) * 512 + c0 + tx];
    __syncthreads();
#pragma unroll
    for (int k = 0; k < 4; k++)
      outp[(long)(c0 + ty + 8 * k) * 2048 + r0 + tx] = (bf16)tile[tx][ty + 8 * k];
  } else if (bid < 6400) {
    int rel = bid - 4352;
    int zz = rel >> 10, rr = rel & 1023;
    int c0 = (rr & 63) * 32, r0 = (rr >> 6) * 32;     // cols 2048, rows 512
    const float* in = zz ? P_feat : P_coord;
    int koff = zz * 512;
    int tx = tid & 31, ty = tid >> 5;
#pragma unroll
    for (int k = 0; k < 4; k++)
      tile[ty + 8 * k][tx] = in[(long)(r0 + ty + 8 * k) * 2048 + c0 + tx];
    __syncthreads();
    int kc = (koff + r0) >> 5;
#pragma unroll
    for (int k = 0; k < 4; k++) {
      int d = c0 + ty + 8 * k;
      PTt[((long)kc * 2048 + d) * 32 + tx] = (bf16)tile[tx][ty + 8 * k];
    }
  } else {
    int g = bid - 6400;
    float c0 = coords[g * 4 + 0], c1 = coords[g * 4 + 1];
    float c2 = coords[g * 4 + 2], c3 = coords[g * 4 + 3];
#pragma unroll
    for (int i = 0; i < 2; i++) {
      int r = tid + i * 256;
      uc[g * RR + r] = c0 * U_coord[r] + c1 * U_coord[RR + r] + c2 * U_coord[2 * RR + r] + c3 * U_coord[3 * RR + r];
      vc[g * RR + r] = c0 * V_coord[r] + c1 * V_coord[RR + r] + c2 * V_coord[2 * RR + r] + c3 * V_coord[3 * RR + r];
    }
  }
}

// ---------------- stage 3: uf/vf = mm @ U_feat / V_feat, 64x128 tile, dbuf -------
// grid (18, 4, 2): 144 blocks. Wave w: A seg w (16 rows), B segs 2w,2w+1 (32 cols).
// LDS [row][32] w/ XOR k-quad swizzle applied on global source (LDS side is
// automatic: lane*16B == (lane>>2)*32elem + (lane&3)*8elem).
__launch_bounds__(256)
__global__ void k_gemm_uv(const bf16* __restrict__ mmb, const bf16* __restrict__ UT,
                          const bf16* __restrict__ VT, float* __restrict__ uf,
                          float* __restrict__ vf) {
  __shared__ bf16 lds2[2][6144];   // per buf: A 64x32 (2048) + B 128x32 (4096)
  const bf16* Bmat = blockIdx.z ? VT : UT;
  float* outp = blockIdx.z ? vf : uf;
  int m0 = blockIdx.x * 64, n0 = blockIdx.y * 128;
  int tid = threadIdx.x, wave = tid >> 6, lane = tid & 63;
  int l15 = lane & 15, qv = lane >> 4;
  int qp_c = qv ^ ((l15 >> 1) & 3);
  int qs = (lane & 3) ^ ((lane >> 3) & 3);

  const bf16* gA = mmb + (long)(m0 + wave * 16 + (lane >> 2)) * 2048 + qs * 8;
  const bf16* gB = Bmat + (long)(n0 + wave * 32 + (lane >> 2)) * 2048 + qs * 8;
  int lA = wave * 512;
  int lB = 2048 + wave * 1024;

  auto stage = [&](int buf, int k0) {
    bf16* db = &lds2[buf][0];
    gl_lds16(gA + k0, db + lA);
    gl_lds16(gB + k0, db + lB);
    gl_lds16(gB + 16 * 2048 + k0, db + lB + 512);
  };

  f32x4 acc[4][2] = {};
  stage(0, 0);
  for (int k0 = 0; k0 < 2048; k0 += 32) {
    int cur = (k0 >> 5) & 1;
    __syncthreads();
    if (k0 + 32 < 2048) stage(cur ^ 1, k0 + 32);
    bf16x8 a[4], b[2];
#pragma unroll
    for (int mt = 0; mt < 4; mt++)
      a[mt] = *(const bf16x8*)(&lds2[cur][0] + (mt * 16 + l15) * 32 + qp_c * 8);
#pragma unroll
    for (int nt = 0; nt < 2; nt++)
      b[nt] = *(const bf16x8*)(&lds2[cur][2048] + (wave * 32 + nt * 16 + l15) * 32 + qp_c * 8);
#pragma unroll
    for (int mt = 0; mt < 4; mt++)
#pragma unroll
      for (int nt = 0; nt < 2; nt++)
        acc[mt][nt] = __builtin_amdgcn_mfma_f32_16x16x32_bf16(a[mt], b[nt], acc[mt][nt], 0, 0, 0);
  }
#pragma unroll
  for (int mt = 0; mt < 4; mt++)
#pragma unroll
    for (int nt = 0; nt < 2; nt++)
#pragma unroll
      for (int r = 0; r < 4; r++) {
        int row = m0 + mt * 16 + qv * 4 + r;
        int col = n0 + wave * 32 + nt * 16 + l15;
        outp[(long)row * RR + col] = acc[mt][nt][r];
      }
}

// ------- stage 4: z_t[kc][row'][32], row' = (bi>>3)*288 + j*8 + (bi&7) -------
__global__ void k_build_z(const float* __restrict__ uc, const float* __restrict__ vc,
                          const float* __restrict__ uf, const float* __restrict__ vf,
                          bf16* __restrict__ z) {
  __shared__ float uL[36 * 128];
  __shared__ float vL[36 * 128];
  int kq = blockIdx.x, b = blockIdx.y, tid = threadIdx.x;
  const float* usrc = (kq < 4) ? uc : uf;
  const float* vsrc = (kq < 4) ? vc : vf;
  int kb = (kq & 3) * 128;
  for (int i = tid; i < 1152; i += 256) {
    int row = i >> 5, kk = (i & 31) * 4;
    long src = (long)(b * 36 + row) * RR + kb + kk;
    *(float4*)&uL[row * 128 + kk] = *(const float4*)(usrc + src);
    *(float4*)&vL[row * 128 + kk] = *(const float4*)(vsrc + src);
  }
  __syncthreads();
  for (int c = tid; c < 41472; c += 256) {
    int kcl = c / 10368;
    int rem = c - kcl * 10368;
    int row = rem >> 3;             // 0..1295 = gl*36 + j
    int x4 = rem & 7;
    int gl = row / 36;
    int j = row - gl * 36;
    int kl = kcl * 32 + x4 * 4;
    float4 u4 = *(const float4*)&uL[gl * 128 + kl];
    float4 v4 = *(const float4*)&vL[j * 128 + kl];
    float x0 = fmaxf(u4.x * v4.x, 0.f), x1 = fmaxf(u4.y * v4.y, 0.f);
    float x2 = fmaxf(u4.z * v4.z, 0.f), x3 = fmaxf(u4.w * v4.w, 0.f);
    bf16x4 o = {(bf16)x0, (bf16)x1, (bf16)x2, (bf16)x3};
    int bi = b * 36 + gl;
    long rowp = (long)(bi >> 3) * 288 + j * 8 + (bi & 7);
    *(bf16x4*)(z + ((long)(kq * 4 + kcl) * ZROWS + rowp) * 32 + x4 * 4) = o;
  }
}

// ---------------- stage 5: main fused GEMM + segmented max + residual ----------------
// 16x16x32 MFMA. Block 288x128, 6 waves 3m x 2n (wave 96r x 64c). Compile-time
// seg roles: wave w stages A segs {3w..3w+2}; waves 0..3 stage B segs {2w,2w+1}.
// [row][32] LDS + XOR k-quad swizzle (conflict-free, R5-verified). acc 96 regs,
// lean staging (2 pointers/wave) -> 3 waves/SIMD -> 2 blocks/CU.
__launch_bounds__(384, 3)
__global__ void k_main(const bf16* __restrict__ z, const bf16* __restrict__ PTt,
                       const float* __restrict__ mm, float* __restrict__ out) {
  __shared__ bf16 lds[2 * BUFE];   // 52 KB
  int bid = blockIdx.x;
  int x = bid & 7, dt = (bid >> 3) & 15, chunk = bid >> 7;
  int go = chunk * 8 + x;          // 0..143 (8-bi groups)
  int d0 = dt * NBLK;
  int tid = threadIdx.x, wave = tid / 64, lane = tid & 63;
  int l15 = lane & 15, qv = lane >> 4;
  int qp_c = qv ^ ((l15 >> 1) & 3);
  int ws = wave >> 1;              // m-strip 0..2 (96 rows)
  int nh = wave & 1;               // n-half (64 cols)

  int qs = (lane & 3) ^ ((lane >> 3) & 3);
  int lroff = (lane >> 2) * 32 + qs * 8;

  // A: wave w -> segs 3w,3w+1,3w+2 ; B: wave w<4 -> segs 2w,2w+1
  const bf16* gA = z + (long)go * (MBLK * 32) + wave * 1536 + lroff;
  const bf16* gB = PTt + (long)d0 * 32 + wave * 1024 + lroff;
  int lA = wave * 1536;
  int lB = ABUF + wave * 1024;

  int sbuf = 0;
  auto stage = [&]() {
    bf16* db = lds + sbuf * BUFE;
    gl_lds16(gA, db + lA);
    gl_lds16(gA + 512, db + lA + 512);
    gl_lds16(gA + 1024, db + lA + 1024);
    gA += (long)ZROWS * 32;
    if (wave < 4) {
      gl_lds16(gB, db + lB);
      gl_lds16(gB + 512, db + lB + 512);
      gB += 2048L * 32;
    }
    sbuf ^= 1;
  };

  f32x4 acc[6][4] = {};
  stage();
  for (int kc = 0; kc < 32; kc++) {
    __syncthreads();
    if (kc < 31) stage();
    const bf16* cur = lds + (kc & 1) * BUFE;
    bf16x8 a[6], b[4];
#pragma unroll
    for (int mt = 0; mt < 6; mt++)
      a[mt] = *(const bf16x8*)(cur + (ws * 96 + mt * 16 + l15) * 32 + qp_c * 8);
#pragma unroll
    for (int nt = 0; nt < 4; nt++)
      b[nt] = *(const bf16x8*)(cur + ABUF + (nh * 64 + nt * 16 + l15) * 32 + qp_c * 8);
#pragma unroll
    for (int mt = 0; mt < 6; mt++)
#pragma unroll
      for (int nt = 0; nt < 4; nt++)
        acc[mt][nt] = __builtin_amdgcn_mfma_f32_16x16x32_bf16(a[mt], b[nt], acc[mt][nt], 0, 0, 0);
  }

  // epilogue: row' = ws*96 + mt*16 + qv*4 + r; gl = (qv*4+r)&7.
  float* pf = (float*)lds;         // 12 KB, aliases buf0 (dead at kc=31)
#pragma unroll
  for (int nt = 0; nt < 4; nt++) {
    int col = nh * 64 + nt * 16 + l15;
    float mx[4];
#pragma unroll
    for (int r = 0; r < 4; r++) {
      mx[r] = acc[0][nt][r];
#pragma unroll
      for (int mt = 1; mt < 6; mt++) mx[r] = fmaxf(mx[r], acc[mt][nt][r]);
      mx[r] = fmaxf(mx[r], __shfl_xor(mx[r], 32, 64));
    }
    if (qv == 0) {
#pragma unroll
      for (int r = 0; r < 4; r++) pf[(ws * 8 + r) * 128 + col] = mx[r];
    } else if (qv == 1) {
#pragma unroll
      for (int r = 0; r < 4; r++) pf[(ws * 8 + 4 + r) * 128 + col] = mx[r];
    }
  }
  __syncthreads();
  for (int o = tid; o < 1024; o += 384) {
    int gl = o >> 7, col = o & 127;
    float v = fmaxf(fmaxf(pf[gl * 128 + col], pf[(8 + gl) * 128 + col]),
                    pf[(16 + gl) * 128 + col]);
    long oa = (long)(go * 8 + gl) * DD + d0 + col;
    out[oa] = v + mm[oa];
  }
}

// ---------------- launcher ----------------
extern "C" void kernel_launch(void* const* d_in, const int* in_sizes, int n_in,
                              void* d_out, int out_size, void* d_ws, size_t ws_size,
                              hipStream_t stream) {
  const float* mm     = (const float*)d_in[0];
  const float* coords = (const float*)d_in[1];
  const float* U_feat = (const float*)d_in[2];
  const float* V_feat = (const float*)d_in[3];
  const float* P_feat = (const float*)d_in[4];
  const float* U_coord= (const float*)d_in[5];
  const float* V_coord= (const float*)d_in[6];
  const float* P_coord= (const float*)d_in[7];
  float* out = (float*)d_out;

  char* ws = (char*)d_ws;
  bf16* z   = (bf16*)(ws + 0);                 //  84,934,656 B  [kc][41472 row'][32]
  bf16* PTt = (bf16*)(ws + 84934656);          //   4,194,304 B  [kc][2048][32]
  bf16* mmb = (bf16*)(ws + 89128960);          //   4,718,592 B
  bf16* UT  = (bf16*)(ws + 93847552);          //   2,097,152 B  [512][2048]
  bf16* VT  = (bf16*)(ws + 95944704);          //   2,097,152 B
  float* uf = (float*)(ws + 98041856);         //   2,359,296 B
  float* vf = (float*)(ws + 100401152);
  float* uc = (float*)(ws + 102760448);
  float* vc = (float*)(ws + 105119744);        // end 107,479,040

  k_prep<<<dim3(7552), dim3(256), 0, stream>>>(mm, coords, U_feat, V_feat, P_feat,
                                               U_coord, V_coord, P_coord,
                                               mmb, UT, VT, PTt, uc, vc);
  k_gemm_uv<<<dim3(18, 4, 2), dim3(256), 0, stream>>>(mmb, UT, VT, uf, vf);
  k_build_z<<<dim3(8, 32), dim3(256), 0, stream>>>(uc, vc, uf, vf, z);
  k_main<<<dim3(2304), dim3(384), 0, stream>>>(z, PTt, mm, out);
}

// Round 8
// 259.729 us; speedup vs baseline: 1.2650x; 1.1630x over previous
//
#include <hip/hip_runtime.h>

// Problem constants
#define BI    1152   // B*N = 32*36
#define NREG  36
#define DD    2048
#define RR    512
#define KK    1024   // 2*R
#define ZROWS (BI*NREG)        // 41472
#define MBLK  144              // 4 bi, rows interleaved j*4+g
#define NBLK  256
#define ABUF  (MBLK*32)        // 4608 elems (9 KB)
#define BBUF  (NBLK*32)        // 8192 elems (16 KB)
#define BUFE  (ABUF+BBUF)      // 12800 elems = 25 KB per buffer

typedef __bf16 bf16;
typedef __bf16 bf16x8 __attribute__((ext_vector_type(8)));
typedef __bf16 bf16x4 __attribute__((ext_vector_type(4)));
typedef float  f32x4  __attribute__((ext_vector_type(4)));

__device__ __forceinline__ void gl_lds16(const void* g, void* l) {
  __builtin_amdgcn_global_load_lds(
      (const __attribute__((address_space(1))) unsigned int*)g,
      (__attribute__((address_space(3))) unsigned int*)l, 16, 0, 0);
}

// ---------------- fused prep: cvt_mm + transpose_uv + transpose_pt + uvcoord -------
__global__ void k_prep(const float* __restrict__ mm, const float* __restrict__ coords,
                       const float* __restrict__ U_feat, const float* __restrict__ V_feat,
                       const float* __restrict__ P_feat, const float* __restrict__ U_coord,
                       const float* __restrict__ V_coord, const float* __restrict__ P_coord,
                       bf16* __restrict__ mmb, bf16* __restrict__ UT, bf16* __restrict__ VT,
                       bf16* __restrict__ PTt, float* __restrict__ uc, float* __restrict__ vc) {
  __shared__ float tile[32][33];
  int bid = blockIdx.x, tid = threadIdx.x;
  if (bid < 2304) {
    int i = bid * 256 + tid;
    float4 v = ((const float4*)mm)[i];
    bf16x4 o = {(bf16)v.x, (bf16)v.y, (bf16)v.z, (bf16)v.w};
    ((bf16x4*)mmb)[i] = o;
  } else if (bid < 4352) {
    int rel = bid - 2304;
    int zz = rel >> 10, rr = rel & 1023;
    int c0 = (rr & 15) * 32, r0 = (rr >> 4) * 32;     // cols 512, rows 2048
    const float* in = zz ? V_feat : U_feat;
    bf16* outp = zz ? VT : UT;
    int tx = tid & 31, ty = tid >> 5;
#pragma unroll
    for (int k = 0; k < 4; k++)
      tile[ty + 8 * k][tx] = in[(long)(r0 + ty + 8 * k) * 512 + c0 + tx];
    __syncthreads();
#pragma unroll
    for (int k = 0; k < 4; k++)
      outp[(long)(c0 + ty + 8 * k) * 2048 + r0 + tx] = (bf16)tile[tx][ty + 8 * k];
  } else if (bid < 6400) {
    int rel = bid - 4352;
    int zz = rel >> 10, rr = rel & 1023;
    int c0 = (rr & 63) * 32, r0 = (rr >> 6) * 32;     // cols 2048, rows 512
    const float* in = zz ? P_feat : P_coord;
    int koff = zz * 512;
    int tx = tid & 31, ty = tid >> 5;
#pragma unroll
    for (int k = 0; k < 4; k++)
      tile[ty + 8 * k][tx] = in[(long)(r0 + ty + 8 * k) * 2048 + c0 + tx];
    __syncthreads();
    int kc = (koff + r0) >> 5;
#pragma unroll
    for (int k = 0; k < 4; k++) {
      int d = c0 + ty + 8 * k;
      PTt[((long)kc * 2048 + d) * 32 + tx] = (bf16)tile[tx][ty + 8 * k];
    }
  } else {
    int g = bid - 6400;
    float c0 = coords[g * 4 + 0], c1 = coords[g * 4 + 1];
    float c2 = coords[g * 4 + 2], c3 = coords[g * 4 + 3];
#pragma unroll
    for (int i = 0; i < 2; i++) {
      int r = tid + i * 256;
      uc[g * RR + r] = c0 * U_coord[r] + c1 * U_coord[RR + r] + c2 * U_coord[2 * RR + r] + c3 * U_coord[3 * RR + r];
      vc[g * RR + r] = c0 * V_coord[r] + c1 * V_coord[RR + r] + c2 * V_coord[2 * RR + r] + c3 * V_coord[3 * RR + r];
    }
  }
}

// ---------------- stage 3: uf/vf = mm @ U_feat / V_feat, 64x128 tile, dbuf -------
__launch_bounds__(256)
__global__ void k_gemm_uv(const bf16* __restrict__ mmb, const bf16* __restrict__ UT,
                          const bf16* __restrict__ VT, float* __restrict__ uf,
                          float* __restrict__ vf) {
  __shared__ bf16 lds2[2][6144];   // per buf: A 64x32 (2048) + B 128x32 (4096)
  const bf16* Bmat = blockIdx.z ? VT : UT;
  float* outp = blockIdx.z ? vf : uf;
  int m0 = blockIdx.x * 64, n0 = blockIdx.y * 128;
  int tid = threadIdx.x, wave = tid >> 6, lane = tid & 63;
  int l15 = lane & 15, qv = lane >> 4;
  int qp_c = qv ^ ((l15 >> 1) & 3);
  int qs = (lane & 3) ^ ((lane >> 3) & 3);

  const bf16* gA = mmb + (long)(m0 + wave * 16 + (lane >> 2)) * 2048 + qs * 8;
  const bf16* gB = Bmat + (long)(n0 + wave * 32 + (lane >> 2)) * 2048 + qs * 8;
  int lA = wave * 512;
  int lB = 2048 + wave * 1024;

  auto stage = [&](int buf, int k0) {
    bf16* db = &lds2[buf][0];
    gl_lds16(gA + k0, db + lA);
    gl_lds16(gB + k0, db + lB);
    gl_lds16(gB + 16 * 2048 + k0, db + lB + 512);
  };

  f32x4 acc[4][2] = {};
  stage(0, 0);
  for (int k0 = 0; k0 < 2048; k0 += 32) {
    int cur = (k0 >> 5) & 1;
    __syncthreads();
    if (k0 + 32 < 2048) stage(cur ^ 1, k0 + 32);
    bf16x8 a[4], b[2];
#pragma unroll
    for (int mt = 0; mt < 4; mt++)
      a[mt] = *(const bf16x8*)(&lds2[cur][0] + (mt * 16 + l15) * 32 + qp_c * 8);
#pragma unroll
    for (int nt = 0; nt < 2; nt++)
      b[nt] = *(const bf16x8*)(&lds2[cur][2048] + (wave * 32 + nt * 16 + l15) * 32 + qp_c * 8);
#pragma unroll
    for (int mt = 0; mt < 4; mt++)
#pragma unroll
      for (int nt = 0; nt < 2; nt++)
        acc[mt][nt] = __builtin_amdgcn_mfma_f32_16x16x32_bf16(a[mt], b[nt], acc[mt][nt], 0, 0, 0);
  }
#pragma unroll
  for (int mt = 0; mt < 4; mt++)
#pragma unroll
    for (int nt = 0; nt < 2; nt++)
#pragma unroll
      for (int r = 0; r < 4; r++) {
        int row = m0 + mt * 16 + qv * 4 + r;
        int col = n0 + wave * 32 + nt * 16 + l15;
        outp[(long)row * RR + col] = acc[mt][nt][r];
      }
}

// ------- stage 4: z_t[kc][row'][32], row' = (bi>>2)*144 + j*4 + (bi&3) -------
__global__ void k_build_z(const float* __restrict__ uc, const float* __restrict__ vc,
                          const float* __restrict__ uf, const float* __restrict__ vf,
                          bf16* __restrict__ z) {
  __shared__ float uL[36 * 128];
  __shared__ float vL[36 * 128];
  int kq = blockIdx.x, b = blockIdx.y, tid = threadIdx.x;
  const float* usrc = (kq < 4) ? uc : uf;
  const float* vsrc = (kq < 4) ? vc : vf;
  int kb = (kq & 3) * 128;
  for (int i = tid; i < 1152; i += 256) {
    int row = i >> 5, kk = (i & 31) * 4;
    long src = (long)(b * 36 + row) * RR + kb + kk;
    *(float4*)&uL[row * 128 + kk] = *(const float4*)(usrc + src);
    *(float4*)&vL[row * 128 + kk] = *(const float4*)(vsrc + src);
  }
  __syncthreads();
  for (int c = tid; c < 41472; c += 256) {
    int kcl = c / 10368;
    int rem = c - kcl * 10368;
    int row = rem >> 3;             // 0..1295 = gl*36 + j
    int x4 = rem & 7;
    int gl = row / 36;
    int j = row - gl * 36;
    int kl = kcl * 32 + x4 * 4;
    float4 u4 = *(const float4*)&uL[gl * 128 + kl];
    float4 v4 = *(const float4*)&vL[j * 128 + kl];
    float x0 = fmaxf(u4.x * v4.x, 0.f), x1 = fmaxf(u4.y * v4.y, 0.f);
    float x2 = fmaxf(u4.z * v4.z, 0.f), x3 = fmaxf(u4.w * v4.w, 0.f);
    bf16x4 o = {(bf16)x0, (bf16)x1, (bf16)x2, (bf16)x3};
    int bi = b * 36 + gl;
    long rowp = (long)(bi >> 2) * 144 + j * 4 + (bi & 3);
    *(bf16x4*)(z + ((long)(kq * 4 + kcl) * ZROWS + rowp) * 32 + x4 * 4) = o;
  }
}

// ---------------- stage 5: main fused GEMM + register max + residual ----------------
// 16x16x32 MFMA. Block 144x256, 4 waves (wave = all 144 rows x 64 cols),
// acc[9][4] = 144 AGPR + ~80 VGPR -> 2 waves/SIMD, 4-wave blocks -> 2 blocks/CU.
// z rows interleaved j*4+g: C-layout gives g = r, j = mt*4+qv -> per-bi max is
// register fmax over mt + shfl_xor over qv. No epilogue LDS/barrier.
__launch_bounds__(256, 2)
__global__ void k_main(const bf16* __restrict__ z, const bf16* __restrict__ PTt,
                       const float* __restrict__ mm, float* __restrict__ out) {
  __shared__ bf16 lds[2 * BUFE];   // 50 KB
  int bid = blockIdx.x;
  // go-major XCD swizzle: all 8 d-tiles of one go share bid&7 -> same XCD L2.
  int x = bid & 7, t = bid >> 3;
  int dt = t & 7, go = (t >> 3) * 8 + x;   // go 0..287 (4-bi groups)
  int d0 = dt * NBLK;
  int tid = threadIdx.x, wave = tid >> 6, lane = tid & 63;
  int l15 = lane & 15, qv = lane >> 4;
  int qp_c = qv ^ ((l15 >> 1) & 3);

  int qs = (lane & 3) ^ ((lane >> 3) & 3);
  int lroff = (lane >> 2) * 32 + qs * 8;

  // staging: A 9 segs (wave w: 2w,2w+1; wave 0 also seg 8), B 16 segs (wave w: 4w..4w+3)
  const bf16* gA = z + (long)go * ABUF + wave * 1024 + lroff;
  const bf16* gB = PTt + (long)d0 * 32 + wave * 2048 + lroff;
  int lA = wave * 1024;
  int lB = ABUF + wave * 2048;

  int sbuf = 0;
  auto stage = [&]() {
    bf16* db = lds + sbuf * BUFE;
    gl_lds16(gA, db + lA);
    gl_lds16(gA + 512, db + lA + 512);
    if (wave == 0) gl_lds16(gA + 4096, db + 4096);
    gl_lds16(gB, db + lB);
    gl_lds16(gB + 512, db + lB + 512);
    gl_lds16(gB + 1024, db + lB + 1024);
    gl_lds16(gB + 1536, db + lB + 1536);
    gA += (long)ZROWS * 32;
    gB += 2048L * 32;
    sbuf ^= 1;
  };

  f32x4 acc[9][4] = {};
  stage();
  for (int kc = 0; kc < 32; kc++) {
    __syncthreads();
    if (kc < 31) stage();
    const bf16* cur = lds + (kc & 1) * BUFE;
    bf16x8 b[4];
#pragma unroll
    for (int nt = 0; nt < 4; nt++)
      b[nt] = *(const bf16x8*)(cur + ABUF + (wave * 64 + nt * 16 + l15) * 32 + qp_c * 8);
#pragma unroll
    for (int mt = 0; mt < 9; mt++) {
      bf16x8 av = *(const bf16x8*)(cur + (mt * 16 + l15) * 32 + qp_c * 8);
#pragma unroll
      for (int nt = 0; nt < 4; nt++)
        acc[mt][nt] = __builtin_amdgcn_mfma_f32_16x16x32_bf16(av, b[nt], acc[mt][nt], 0, 0, 0);
    }
  }

  // epilogue: row-in-block = mt*16 + qv*4 + r = j*4 + g -> g = r, j = mt*4 + qv.
#pragma unroll
  for (int nt = 0; nt < 4; nt++) {
    float mx[4];
#pragma unroll
    for (int r = 0; r < 4; r++) {
      mx[r] = acc[0][nt][r];
#pragma unroll
      for (int mt = 1; mt < 9; mt++) mx[r] = fmaxf(mx[r], acc[mt][nt][r]);
      mx[r] = fmaxf(mx[r], __shfl_xor(mx[r], 16, 64));
      mx[r] = fmaxf(mx[r], __shfl_xor(mx[r], 32, 64));
    }
    if (lane < 16) {
      int col = d0 + wave * 64 + nt * 16 + lane;
#pragma unroll
      for (int r = 0; r < 4; r++) {
        long oa = (long)(go * 4 + r) * DD + col;
        out[oa] = mx[r] + mm[oa];
      }
    }
  }
}

// ---------------- launcher ----------------
extern "C" void kernel_launch(void* const* d_in, const int* in_sizes, int n_in,
                              void* d_out, int out_size, void* d_ws, size_t ws_size,
                              hipStream_t stream) {
  const float* mm     = (const float*)d_in[0];
  const float* coords = (const float*)d_in[1];
  const float* U_feat = (const float*)d_in[2];
  const float* V_feat = (const float*)d_in[3];
  const float* P_feat = (const float*)d_in[4];
  const float* U_coord= (const float*)d_in[5];
  const float* V_coord= (const float*)d_in[6];
  const float* P_coord= (const float*)d_in[7];
  float* out = (float*)d_out;

  char* ws = (char*)d_ws;
  bf16* z   = (bf16*)(ws + 0);                 //  84,934,656 B  [kc][41472 row'][32]
  bf16* PTt = (bf16*)(ws + 84934656);          //   4,194,304 B  [kc][2048][32]
  bf16* mmb = (bf16*)(ws + 89128960);          //   4,718,592 B
  bf16* UT  = (bf16*)(ws + 93847552);          //   2,097,152 B  [512][2048]
  bf16* VT  = (bf16*)(ws + 95944704);          //   2,097,152 B
  float* uf = (float*)(ws + 98041856);         //   2,359,296 B
  float* vf = (float*)(ws + 100401152);
  float* uc = (float*)(ws + 102760448);
  float* vc = (float*)(ws + 105119744);        // end 107,479,040

  k_prep<<<dim3(7552), dim3(256), 0, stream>>>(mm, coords, U_feat, V_feat, P_feat,
                                               U_coord, V_coord, P_coord,
                                               mmb, UT, VT, PTt, uc, vc);
  k_gemm_uv<<<dim3(18, 4, 2), dim3(256), 0, stream>>>(mmb, UT, VT, uf, vf);
  k_build_z<<<dim3(8, 32), dim3(256), 0, stream>>>(uc, vc, uf, vf, z);
  k_main<<<dim3(2304), dim3(256), 0, stream>>>(z, PTt, mm, out);
}

// Round 9
// 255.867 us; speedup vs baseline: 1.2841x; 1.0151x over previous
//
#include <hip/hip_runtime.h>

// Problem constants
#define BI    1152   // B*N = 32*36
#define NREG  36
#define DD    2048
#define RR    512
#define KK    1024   // 2*R
#define ZROWS (BI*NREG)        // 41472
#define MBLK  144              // 4 bi, rows interleaved j*4+g
#define NBLK  256
#define ABUF  (MBLK*32)        // 4608 elems (9 KB)

typedef __bf16 bf16;
typedef __bf16 bf16x8 __attribute__((ext_vector_type(8)));
typedef __bf16 bf16x4 __attribute__((ext_vector_type(4)));
typedef float  f32x4  __attribute__((ext_vector_type(4)));

__device__ __forceinline__ void gl_lds16(const void* g, void* l) {
  __builtin_amdgcn_global_load_lds(
      (const __attribute__((address_space(1))) unsigned int*)g,
      (__attribute__((address_space(3))) unsigned int*)l, 16, 0, 0);
}

// ---------------- fused prep: cvt_mm + transpose_uv + transpose_pt + uvcoord -------
__global__ void k_prep(const float* __restrict__ mm, const float* __restrict__ coords,
                       const float* __restrict__ U_feat, const float* __restrict__ V_feat,
                       const float* __restrict__ P_feat, const float* __restrict__ U_coord,
                       const float* __restrict__ V_coord, const float* __restrict__ P_coord,
                       bf16* __restrict__ mmb, bf16* __restrict__ UT, bf16* __restrict__ VT,
                       bf16* __restrict__ PTt, float* __restrict__ uc, float* __restrict__ vc) {
  __shared__ float tile[32][33];
  int bid = blockIdx.x, tid = threadIdx.x;
  if (bid < 2304) {
    int i = bid * 256 + tid;
    float4 v = ((const float4*)mm)[i];
    bf16x4 o = {(bf16)v.x, (bf16)v.y, (bf16)v.z, (bf16)v.w};
    ((bf16x4*)mmb)[i] = o;
  } else if (bid < 4352) {
    int rel = bid - 2304;
    int zz = rel >> 10, rr = rel & 1023;
    int c0 = (rr & 15) * 32, r0 = (rr >> 4) * 32;     // cols 512, rows 2048
    const float* in = zz ? V_feat : U_feat;
    bf16* outp = zz ? VT : UT;
    int tx = tid & 31, ty = tid >> 5;
#pragma unroll
    for (int k = 0; k < 4; k++)
      tile[ty + 8 * k][tx] = in[(long)(r0 + ty + 8 * k) * 512 + c0 + tx];
    __syncthreads();
#pragma unroll
    for (int k = 0; k < 4; k++)
      outp[(long)(c0 + ty + 8 * k) * 2048 + r0 + tx] = (bf16)tile[tx][ty + 8 * k];
  } else if (bid < 6400) {
    int rel = bid - 4352;
    int zz = rel >> 10, rr = rel & 1023;
    int c0 = (rr & 63) * 32, r0 = (rr >> 6) * 32;     // cols 2048, rows 512
    const float* in = zz ? P_feat : P_coord;
    int koff = zz * 512;
    int tx = tid & 31, ty = tid >> 5;
#pragma unroll
    for (int k = 0; k < 4; k++)
      tile[ty + 8 * k][tx] = in[(long)(r0 + ty + 8 * k) * 2048 + c0 + tx];
    __syncthreads();
    int kc = (koff + r0) >> 5;
#pragma unroll
    for (int k = 0; k < 4; k++) {
      int d = c0 + ty + 8 * k;
      PTt[((long)kc * 2048 + d) * 32 + tx] = (bf16)tile[tx][ty + 8 * k];
    }
  } else {
    int g = bid - 6400;
    float c0 = coords[g * 4 + 0], c1 = coords[g * 4 + 1];
    float c2 = coords[g * 4 + 2], c3 = coords[g * 4 + 3];
#pragma unroll
    for (int i = 0; i < 2; i++) {
      int r = tid + i * 256;
      uc[g * RR + r] = c0 * U_coord[r] + c1 * U_coord[RR + r] + c2 * U_coord[2 * RR + r] + c3 * U_coord[3 * RR + r];
      vc[g * RR + r] = c0 * V_coord[r] + c1 * V_coord[RR + r] + c2 * V_coord[2 * RR + r] + c3 * V_coord[3 * RR + r];
    }
  }
}

// ------- stage 3: uf/vf partials (split-K=2), 64x128 tile, dbuf -------
// grid (18, 4, 4): z = uv*2 + kh. Each block does K in [kh*1024, kh*1024+1024).
__launch_bounds__(256)
__global__ void k_gemm_uv(const bf16* __restrict__ mmb, const bf16* __restrict__ UT,
                          const bf16* __restrict__ VT, float* __restrict__ uf,
                          float* __restrict__ vf, float* __restrict__ uf2,
                          float* __restrict__ vf2) {
  __shared__ bf16 lds2[2][6144];   // per buf: A 64x32 (2048) + B 128x32 (4096)
  int uv = blockIdx.z >> 1, kh = blockIdx.z & 1;
  const bf16* Bmat = uv ? VT : UT;
  float* outp = uv ? (kh ? vf2 : vf) : (kh ? uf2 : uf);
  int m0 = blockIdx.x * 64, n0 = blockIdx.y * 128;
  int kbase = kh * 1024;
  int tid = threadIdx.x, wave = tid >> 6, lane = tid & 63;
  int l15 = lane & 15, qv = lane >> 4;
  int qp_c = qv ^ ((l15 >> 1) & 3);
  int qs = (lane & 3) ^ ((lane >> 3) & 3);

  const bf16* gA = mmb + (long)(m0 + wave * 16 + (lane >> 2)) * 2048 + kbase + qs * 8;
  const bf16* gB = Bmat + (long)(n0 + wave * 32 + (lane >> 2)) * 2048 + kbase + qs * 8;
  int lA = wave * 512;
  int lB = 2048 + wave * 1024;

  auto stage = [&](int buf, int k0) {
    bf16* db = &lds2[buf][0];
    gl_lds16(gA + k0, db + lA);
    gl_lds16(gB + k0, db + lB);
    gl_lds16(gB + 16 * 2048 + k0, db + lB + 512);
  };

  f32x4 acc[4][2] = {};
  stage(0, 0);
  for (int k0 = 0; k0 < 1024; k0 += 32) {
    int cur = (k0 >> 5) & 1;
    __syncthreads();
    if (k0 + 32 < 1024) stage(cur ^ 1, k0 + 32);
    bf16x8 a[4], b[2];
#pragma unroll
    for (int mt = 0; mt < 4; mt++)
      a[mt] = *(const bf16x8*)(&lds2[cur][0] + (mt * 16 + l15) * 32 + qp_c * 8);
#pragma unroll
    for (int nt = 0; nt < 2; nt++)
      b[nt] = *(const bf16x8*)(&lds2[cur][2048] + (wave * 32 + nt * 16 + l15) * 32 + qp_c * 8);
#pragma unroll
    for (int mt = 0; mt < 4; mt++)
#pragma unroll
      for (int nt = 0; nt < 2; nt++)
        acc[mt][nt] = __builtin_amdgcn_mfma_f32_16x16x32_bf16(a[mt], b[nt], acc[mt][nt], 0, 0, 0);
  }
#pragma unroll
  for (int mt = 0; mt < 4; mt++)
#pragma unroll
    for (int nt = 0; nt < 2; nt++)
#pragma unroll
      for (int r = 0; r < 4; r++) {
        int row = m0 + mt * 16 + qv * 4 + r;
        int col = n0 + wave * 32 + nt * 16 + l15;
        outp[(long)row * RR + col] = acc[mt][nt][r];
      }
}

// ------- stage 4: z_t[kc][row'][32], row' = (bi>>2)*144 + j*4 + (bi&3) -------
// grid (8, 32, 2): z splits the write loop.
__global__ void k_build_z(const float* __restrict__ uc, const float* __restrict__ vc,
                          const float* __restrict__ uf, const float* __restrict__ vf,
                          const float* __restrict__ uf2, const float* __restrict__ vf2,
                          bf16* __restrict__ z) {
  __shared__ float uL[36 * 128];
  __shared__ float vL[36 * 128];
  int kq = blockIdx.x, b = blockIdx.y, tid = threadIdx.x;
  int kb = (kq & 3) * 128;
  for (int i = tid; i < 1152; i += 256) {
    int row = i >> 5, kk = (i & 31) * 4;
    long src = (long)(b * 36 + row) * RR + kb + kk;
    float4 u4, v4;
    if (kq < 4) {
      u4 = *(const float4*)(uc + src);
      v4 = *(const float4*)(vc + src);
    } else {
      float4 a1 = *(const float4*)(uf + src), a2 = *(const float4*)(uf2 + src);
      float4 b1 = *(const float4*)(vf + src), b2 = *(const float4*)(vf2 + src);
      u4.x = a1.x + a2.x; u4.y = a1.y + a2.y; u4.z = a1.z + a2.z; u4.w = a1.w + a2.w;
      v4.x = b1.x + b2.x; v4.y = b1.y + b2.y; v4.z = b1.z + b2.z; v4.w = b1.w + b2.w;
    }
    *(float4*)&uL[row * 128 + kk] = u4;
    *(float4*)&vL[row * 128 + kk] = v4;
  }
  __syncthreads();
  int cbase = blockIdx.z * 20736;
  for (int c = cbase + tid; c < cbase + 20736; c += 256) {
    int kcl = c / 10368;
    int rem = c - kcl * 10368;
    int row = rem >> 3;             // 0..1295 = gl*36 + j
    int x4 = rem & 7;
    int gl = row / 36;
    int j = row - gl * 36;
    int kl = kcl * 32 + x4 * 4;
    float4 u4 = *(const float4*)&uL[gl * 128 + kl];
    float4 v4 = *(const float4*)&vL[j * 128 + kl];
    float x0 = fmaxf(u4.x * v4.x, 0.f), x1 = fmaxf(u4.y * v4.y, 0.f);
    float x2 = fmaxf(u4.z * v4.z, 0.f), x3 = fmaxf(u4.w * v4.w, 0.f);
    bf16x4 o = {(bf16)x0, (bf16)x1, (bf16)x2, (bf16)x3};
    int bi = b * 36 + gl;
    long rowp = (long)(bi >> 2) * 144 + j * 4 + (bi & 3);
    *(bf16x4*)(z + ((long)(kq * 4 + kcl) * ZROWS + rowp) * 32 + x4 * 4) = o;
  }
}

// ---------------- stage 5: main fused GEMM + register max + residual ----------------
// 16x16x32 MFMA. Block 144x256, 4 waves (wave = 144 rows x private 64 cols).
// A via LDS ([row][32] + XOR swizzle, conflict-free); B has NO inter-wave reuse ->
// loaded straight from global (L2) into registers, ping-pong prefetched over a
// 2-unrolled k-loop. LDS traffic/block-kstep: 45 KB (was 77) -> MFMA-bound.
__launch_bounds__(256, 2)
__global__ void k_main(const bf16* __restrict__ z, const bf16* __restrict__ PTt,
                       const float* __restrict__ mm, float* __restrict__ out) {
  __shared__ bf16 lds[2 * ABUF];   // 18 KB, A only
  int bid = blockIdx.x;
  int x = bid & 7, t = bid >> 3;
  int dt = t & 7, go = (t >> 3) * 8 + x;   // go 0..287 (4-bi groups)
  int d0 = dt * NBLK;
  int tid = threadIdx.x, wave = tid >> 6, lane = tid & 63;
  int l15 = lane & 15, qv = lane >> 4;
  int qp_c = qv ^ ((l15 >> 1) & 3);
  int qs = (lane & 3) ^ ((lane >> 3) & 3);
  int lroff = (lane >> 2) * 32 + qs * 8;

  const bf16* gA = z + (long)go * ABUF + wave * 1024 + lroff;
  int lA = wave * 1024;
  // B direct from global: plain octet qv (no swizzle — no LDS round-trip)
  const bf16* gB = PTt + (long)(d0 + wave * 64 + l15) * 32 + qv * 8;

  auto stageA = [&](int buf) {
    bf16* db = lds + buf * ABUF;
    gl_lds16(gA, db + lA);
    gl_lds16(gA + 512, db + lA + 512);
    if (wave == 0) gl_lds16(gA + 4096, db + 4096);
    gA += (long)ZROWS * 32;
  };
  auto loadB = [&](int kc, bf16x8* b) {
    const bf16* p = gB + (long)kc * (2048 * 32);
#pragma unroll
    for (int nt = 0; nt < 4; nt++)
      b[nt] = *(const bf16x8*)(p + nt * 512);
  };

  f32x4 acc[9][4] = {};
  bf16x8 b0[4], b1[4];
  stageA(0);
  loadB(0, b0);
  for (int kc = 0; kc < 32; kc += 2) {
    __syncthreads();
    if (kc + 1 < 32) { stageA(1); loadB(kc + 1, b1); }
    {
      const bf16* cur = lds;
#pragma unroll
      for (int mt = 0; mt < 9; mt++) {
        bf16x8 av = *(const bf16x8*)(cur + (mt * 16 + l15) * 32 + qp_c * 8);
#pragma unroll
        for (int nt = 0; nt < 4; nt++)
          acc[mt][nt] = __builtin_amdgcn_mfma_f32_16x16x32_bf16(av, b0[nt], acc[mt][nt], 0, 0, 0);
      }
    }
    __syncthreads();
    if (kc + 2 < 32) { stageA(0); loadB(kc + 2, b0); }
    {
      const bf16* cur = lds + ABUF;
#pragma unroll
      for (int mt = 0; mt < 9; mt++) {
        bf16x8 av = *(const bf16x8*)(cur + (mt * 16 + l15) * 32 + qp_c * 8);
#pragma unroll
        for (int nt = 0; nt < 4; nt++)
          acc[mt][nt] = __builtin_amdgcn_mfma_f32_16x16x32_bf16(av, b1[nt], acc[mt][nt], 0, 0, 0);
      }
    }
  }

  // epilogue: row-in-block = mt*16 + qv*4 + r = j*4 + g -> g = r, j = mt*4 + qv.
#pragma unroll
  for (int nt = 0; nt < 4; nt++) {
    float mx[4];
#pragma unroll
    for (int r = 0; r < 4; r++) {
      mx[r] = acc[0][nt][r];
#pragma unroll
      for (int mt = 1; mt < 9; mt++) mx[r] = fmaxf(mx[r], acc[mt][nt][r]);
      mx[r] = fmaxf(mx[r], __shfl_xor(mx[r], 16, 64));
      mx[r] = fmaxf(mx[r], __shfl_xor(mx[r], 32, 64));
    }
    if (lane < 16) {
      int col = d0 + wave * 64 + nt * 16 + lane;
#pragma unroll
      for (int r = 0; r < 4; r++) {
        long oa = (long)(go * 4 + r) * DD + col;
        out[oa] = mx[r] + mm[oa];
      }
    }
  }
}

// ---------------- launcher ----------------
extern "C" void kernel_launch(void* const* d_in, const int* in_sizes, int n_in,
                              void* d_out, int out_size, void* d_ws, size_t ws_size,
                              hipStream_t stream) {
  const float* mm     = (const float*)d_in[0];
  const float* coords = (const float*)d_in[1];
  const float* U_feat = (const float*)d_in[2];
  const float* V_feat = (const float*)d_in[3];
  const float* P_feat = (const float*)d_in[4];
  const float* U_coord= (const float*)d_in[5];
  const float* V_coord= (const float*)d_in[6];
  const float* P_coord= (const float*)d_in[7];
  float* out = (float*)d_out;

  char* ws = (char*)d_ws;
  bf16* z   = (bf16*)(ws + 0);                 //  84,934,656 B  [kc][41472 row'][32]
  bf16* PTt = (bf16*)(ws + 84934656);          //   4,194,304 B  [kc][2048][32]
  bf16* mmb = (bf16*)(ws + 89128960);          //   4,718,592 B
  bf16* UT  = (bf16*)(ws + 93847552);          //   2,097,152 B  [512][2048]
  bf16* VT  = (bf16*)(ws + 95944704);          //   2,097,152 B
  float* uf = (float*)(ws + 98041856);         //   2,359,296 B
  float* vf = (float*)(ws + 100401152);
  float* uc = (float*)(ws + 102760448);
  float* vc = (float*)(ws + 105119744);
  float* uf2= (float*)(ws + 107479040);
  float* vf2= (float*)(ws + 109838336);        // end 112,197,632 (R1 proved ws >= 135 MB)

  k_prep<<<dim3(7552), dim3(256), 0, stream>>>(mm, coords, U_feat, V_feat, P_feat,
                                               U_coord, V_coord, P_coord,
                                               mmb, UT, VT, PTt, uc, vc);
  k_gemm_uv<<<dim3(18, 4, 4), dim3(256), 0, stream>>>(mmb, UT, VT, uf, vf, uf2, vf2);
  k_build_z<<<dim3(8, 32, 2), dim3(256), 0, stream>>>(uc, vc, uf, vf, uf2, vf2, z);
  k_main<<<dim3(2304), dim3(256), 0, stream>>>(z, PTt, mm, out);
}

// Round 10
// 247.411 us; speedup vs baseline: 1.3280x; 1.0342x over previous
//
#include <hip/hip_runtime.h>

// Problem constants
#define BI    1152   // B*N = 32*36
#define NREG  36
#define DD    2048
#define RR    512
#define KK    1024   // 2*R
#define ZROWS (BI*NREG)        // 41472
#define MBLK  144              // 4 bi, rows interleaved j*4+g
#define NBLK  256
#define ABUF  (MBLK*32)        // 4608 elems (9 KB)
#define BBUF  (NBLK*32)        // 8192 elems (16 KB)
#define BUFE  (ABUF+BBUF)      // 12800 elems = 25 KB per buffer

typedef __bf16 bf16;
typedef __bf16 bf16x8 __attribute__((ext_vector_type(8)));
typedef __bf16 bf16x4 __attribute__((ext_vector_type(4)));
typedef float  f32x4  __attribute__((ext_vector_type(4)));

__device__ __forceinline__ void gl_lds16(const void* g, void* l) {
  __builtin_amdgcn_global_load_lds(
      (const __attribute__((address_space(1))) unsigned int*)g,
      (__attribute__((address_space(3))) unsigned int*)l, 16, 0, 0);
}

// ---------------- fused prep: cvt_mm + transpose_uv + transpose_pt + uvcoord -------
__global__ void k_prep(const float* __restrict__ mm, const float* __restrict__ coords,
                       const float* __restrict__ U_feat, const float* __restrict__ V_feat,
                       const float* __restrict__ P_feat, const float* __restrict__ U_coord,
                       const float* __restrict__ V_coord, const float* __restrict__ P_coord,
                       bf16* __restrict__ mmb, bf16* __restrict__ UT, bf16* __restrict__ VT,
                       bf16* __restrict__ PTt, float* __restrict__ uc, float* __restrict__ vc) {
  __shared__ float tile[32][33];
  int bid = blockIdx.x, tid = threadIdx.x;
  if (bid < 2304) {
    int i = bid * 256 + tid;
    float4 v = ((const float4*)mm)[i];
    bf16x4 o = {(bf16)v.x, (bf16)v.y, (bf16)v.z, (bf16)v.w};
    ((bf16x4*)mmb)[i] = o;
  } else if (bid < 4352) {
    int rel = bid - 2304;
    int zz = rel >> 10, rr = rel & 1023;
    int c0 = (rr & 15) * 32, r0 = (rr >> 4) * 32;     // cols 512, rows 2048
    const float* in = zz ? V_feat : U_feat;
    bf16* outp = zz ? VT : UT;
    int tx = tid & 31, ty = tid >> 5;
#pragma unroll
    for (int k = 0; k < 4; k++)
      tile[ty + 8 * k][tx] = in[(long)(r0 + ty + 8 * k) * 512 + c0 + tx];
    __syncthreads();
#pragma unroll
    for (int k = 0; k < 4; k++)
      outp[(long)(c0 + ty + 8 * k) * 2048 + r0 + tx] = (bf16)tile[tx][ty + 8 * k];
  } else if (bid < 6400) {
    int rel = bid - 4352;
    int zz = rel >> 10, rr = rel & 1023;
    int c0 = (rr & 63) * 32, r0 = (rr >> 6) * 32;     // cols 2048, rows 512
    const float* in = zz ? P_feat : P_coord;
    int koff = zz * 512;
    int tx = tid & 31, ty = tid >> 5;
#pragma unroll
    for (int k = 0; k < 4; k++)
      tile[ty + 8 * k][tx] = in[(long)(r0 + ty + 8 * k) * 2048 + c0 + tx];
    __syncthreads();
    int kc = (koff + r0) >> 5;
#pragma unroll
    for (int k = 0; k < 4; k++) {
      int d = c0 + ty + 8 * k;
      PTt[((long)kc * 2048 + d) * 32 + tx] = (bf16)tile[tx][ty + 8 * k];
    }
  } else {
    int g = bid - 6400;
    float c0 = coords[g * 4 + 0], c1 = coords[g * 4 + 1];
    float c2 = coords[g * 4 + 2], c3 = coords[g * 4 + 3];
#pragma unroll
    for (int i = 0; i < 2; i++) {
      int r = tid + i * 256;
      uc[g * RR + r] = c0 * U_coord[r] + c1 * U_coord[RR + r] + c2 * U_coord[2 * RR + r] + c3 * U_coord[3 * RR + r];
      vc[g * RR + r] = c0 * V_coord[r] + c1 * V_coord[RR + r] + c2 * V_coord[2 * RR + r] + c3 * V_coord[3 * RR + r];
    }
  }
}

// ------- stage 3: uf/vf partials (split-K=2), 64x128 tile, dbuf -------
__launch_bounds__(256)
__global__ void k_gemm_uv(const bf16* __restrict__ mmb, const bf16* __restrict__ UT,
                          const bf16* __restrict__ VT, float* __restrict__ uf,
                          float* __restrict__ vf, float* __restrict__ uf2,
                          float* __restrict__ vf2) {
  __shared__ bf16 lds2[2][6144];   // per buf: A 64x32 (2048) + B 128x32 (4096)
  int uv = blockIdx.z >> 1, kh = blockIdx.z & 1;
  const bf16* Bmat = uv ? VT : UT;
  float* outp = uv ? (kh ? vf2 : vf) : (kh ? uf2 : uf);
  int m0 = blockIdx.x * 64, n0 = blockIdx.y * 128;
  int kbase = kh * 1024;
  int tid = threadIdx.x, wave = tid >> 6, lane = tid & 63;
  int l15 = lane & 15, qv = lane >> 4;
  int qp_c = qv ^ ((l15 >> 1) & 3);
  int qs = (lane & 3) ^ ((lane >> 3) & 3);

  const bf16* gA = mmb + (long)(m0 + wave * 16 + (lane >> 2)) * 2048 + kbase + qs * 8;
  const bf16* gB = Bmat + (long)(n0 + wave * 32 + (lane >> 2)) * 2048 + kbase + qs * 8;
  int lA = wave * 512;
  int lB = 2048 + wave * 1024;

  auto stage = [&](int buf, int k0) {
    bf16* db = &lds2[buf][0];
    gl_lds16(gA + k0, db + lA);
    gl_lds16(gB + k0, db + lB);
    gl_lds16(gB + 16 * 2048 + k0, db + lB + 512);
  };

  f32x4 acc[4][2] = {};
  stage(0, 0);
  for (int k0 = 0; k0 < 1024; k0 += 32) {
    int cur = (k0 >> 5) & 1;
    __syncthreads();
    if (k0 + 32 < 1024) stage(cur ^ 1, k0 + 32);
    bf16x8 a[4], b[2];
#pragma unroll
    for (int mt = 0; mt < 4; mt++)
      a[mt] = *(const bf16x8*)(&lds2[cur][0] + (mt * 16 + l15) * 32 + qp_c * 8);
#pragma unroll
    for (int nt = 0; nt < 2; nt++)
      b[nt] = *(const bf16x8*)(&lds2[cur][2048] + (wave * 32 + nt * 16 + l15) * 32 + qp_c * 8);
#pragma unroll
    for (int mt = 0; mt < 4; mt++)
#pragma unroll
      for (int nt = 0; nt < 2; nt++)
        acc[mt][nt] = __builtin_amdgcn_mfma_f32_16x16x32_bf16(a[mt], b[nt], acc[mt][nt], 0, 0, 0);
  }
#pragma unroll
  for (int mt = 0; mt < 4; mt++)
#pragma unroll
    for (int nt = 0; nt < 2; nt++)
#pragma unroll
      for (int r = 0; r < 4; r++) {
        int row = m0 + mt * 16 + qv * 4 + r;
        int col = n0 + wave * 32 + nt * 16 + l15;
        outp[(long)row * RR + col] = acc[mt][nt][r];
      }
}

// ------- stage 4: z_t[kc][row'][32], row' = (bi>>2)*144 + j*4 + (bi&3) -------
__global__ void k_build_z(const float* __restrict__ uc, const float* __restrict__ vc,
                          const float* __restrict__ uf, const float* __restrict__ vf,
                          const float* __restrict__ uf2, const float* __restrict__ vf2,
                          bf16* __restrict__ z) {
  __shared__ float uL[36 * 128];
  __shared__ float vL[36 * 128];
  int kq = blockIdx.x, b = blockIdx.y, tid = threadIdx.x;
  int kb = (kq & 3) * 128;
  for (int i = tid; i < 1152; i += 256) {
    int row = i >> 5, kk = (i & 31) * 4;
    long src = (long)(b * 36 + row) * RR + kb + kk;
    float4 u4, v4;
    if (kq < 4) {
      u4 = *(const float4*)(uc + src);
      v4 = *(const float4*)(vc + src);
    } else {
      float4 a1 = *(const float4*)(uf + src), a2 = *(const float4*)(uf2 + src);
      float4 b1 = *(const float4*)(vf + src), b2 = *(const float4*)(vf2 + src);
      u4.x = a1.x + a2.x; u4.y = a1.y + a2.y; u4.z = a1.z + a2.z; u4.w = a1.w + a2.w;
      v4.x = b1.x + b2.x; v4.y = b1.y + b2.y; v4.z = b1.z + b2.z; v4.w = b1.w + b2.w;
    }
    *(float4*)&uL[row * 128 + kk] = u4;
    *(float4*)&vL[row * 128 + kk] = v4;
  }
  __syncthreads();
  int cbase = blockIdx.z * 20736;
  for (int c = cbase + tid; c < cbase + 20736; c += 256) {
    int kcl = c / 10368;
    int rem = c - kcl * 10368;
    int row = rem >> 3;             // 0..1295 = gl*36 + j
    int x4 = rem & 7;
    int gl = row / 36;
    int j = row - gl * 36;
    int kl = kcl * 32 + x4 * 4;
    float4 u4 = *(const float4*)&uL[gl * 128 + kl];
    float4 v4 = *(const float4*)&vL[j * 128 + kl];
    float x0 = fmaxf(u4.x * v4.x, 0.f), x1 = fmaxf(u4.y * v4.y, 0.f);
    float x2 = fmaxf(u4.z * v4.z, 0.f), x3 = fmaxf(u4.w * v4.w, 0.f);
    bf16x4 o = {(bf16)x0, (bf16)x1, (bf16)x2, (bf16)x3};
    int bi = b * 36 + gl;
    long rowp = (long)(bi >> 2) * 144 + j * 4 + (bi & 3);
    *(bf16x4*)(z + ((long)(kq * 4 + kcl) * ZROWS + rowp) * 32 + x4 * 4) = o;
  }
}

// ---------------- stage 5: main fused GEMM + register max + residual ----------------
// R8-proven structure (141 us, MfmaUtil 56%, conflicts 0, 2 blocks/CU): 16x16x32,
// block 144x256, 4 waves (wave = 144 rows x private 64 cols), A+B both staged via
// global_load_lds into [row][32]+XOR-swizzle LDS, 1 barrier/kstep stage-ahead dbuf.
// This sits on the LDS-port roofline (~77KB/kstep/block ~= 616 cyc; x2 blocks ~= 1175
// measured). z rows interleaved j*4+g -> epilogue max is register+shfl only.
__launch_bounds__(256, 2)
__global__ void k_main(const bf16* __restrict__ z, const bf16* __restrict__ PTt,
                       const float* __restrict__ mm, float* __restrict__ out) {
  __shared__ bf16 lds[2 * BUFE];   // 50 KB
  int bid = blockIdx.x;
  int x = bid & 7, t = bid >> 3;
  int dt = t & 7, go = (t >> 3) * 8 + x;   // go 0..287 (4-bi groups)
  int d0 = dt * NBLK;
  int tid = threadIdx.x, wave = tid >> 6, lane = tid & 63;
  int l15 = lane & 15, qv = lane >> 4;
  int qp_c = qv ^ ((l15 >> 1) & 3);
  int qs = (lane & 3) ^ ((lane >> 3) & 3);
  int lroff = (lane >> 2) * 32 + qs * 8;

  const bf16* gA = z + (long)go * ABUF + wave * 1024 + lroff;
  const bf16* gB = PTt + (long)d0 * 32 + wave * 2048 + lroff;
  int lA = wave * 1024;
  int lB = ABUF + wave * 2048;

  int sbuf = 0;
  auto stage = [&]() {
    bf16* db = lds + sbuf * BUFE;
    gl_lds16(gA, db + lA);
    gl_lds16(gA + 512, db + lA + 512);
    if (wave == 0) gl_lds16(gA + 4096, db + 4096);
    gl_lds16(gB, db + lB);
    gl_lds16(gB + 512, db + lB + 512);
    gl_lds16(gB + 1024, db + lB + 1024);
    gl_lds16(gB + 1536, db + lB + 1536);
    gA += (long)ZROWS * 32;
    gB += 2048L * 32;
    sbuf ^= 1;
  };

  f32x4 acc[9][4] = {};
  stage();
  for (int kc = 0; kc < 32; kc++) {
    __syncthreads();
    if (kc < 31) stage();
    const bf16* cur = lds + (kc & 1) * BUFE;
    bf16x8 b[4];
#pragma unroll
    for (int nt = 0; nt < 4; nt++)
      b[nt] = *(const bf16x8*)(cur + ABUF + (wave * 64 + nt * 16 + l15) * 32 + qp_c * 8);
#pragma unroll
    for (int mt = 0; mt < 9; mt++) {
      bf16x8 av = *(const bf16x8*)(cur + (mt * 16 + l15) * 32 + qp_c * 8);
#pragma unroll
      for (int nt = 0; nt < 4; nt++)
        acc[mt][nt] = __builtin_amdgcn_mfma_f32_16x16x32_bf16(av, b[nt], acc[mt][nt], 0, 0, 0);
    }
  }

  // epilogue: row-in-block = mt*16 + qv*4 + r = j*4 + g -> g = r, j = mt*4 + qv.
#pragma unroll
  for (int nt = 0; nt < 4; nt++) {
    float mx[4];
#pragma unroll
    for (int r = 0; r < 4; r++) {
      mx[r] = acc[0][nt][r];
#pragma unroll
      for (int mt = 1; mt < 9; mt++) mx[r] = fmaxf(mx[r], acc[mt][nt][r]);
      mx[r] = fmaxf(mx[r], __shfl_xor(mx[r], 16, 64));
      mx[r] = fmaxf(mx[r], __shfl_xor(mx[r], 32, 64));
    }
    if (lane < 16) {
      int col = d0 + wave * 64 + nt * 16 + lane;
#pragma unroll
      for (int r = 0; r < 4; r++) {
        long oa = (long)(go * 4 + r) * DD + col;
        out[oa] = mx[r] + mm[oa];
      }
    }
  }
}

// ---------------- launcher ----------------
extern "C" void kernel_launch(void* const* d_in, const int* in_sizes, int n_in,
                              void* d_out, int out_size, void* d_ws, size_t ws_size,
                              hipStream_t stream) {
  const float* mm     = (const float*)d_in[0];
  const float* coords = (const float*)d_in[1];
  const float* U_feat = (const float*)d_in[2];
  const float* V_feat = (const float*)d_in[3];
  const float* P_feat = (const float*)d_in[4];
  const float* U_coord= (const float*)d_in[5];
  const float* V_coord= (const float*)d_in[6];
  const float* P_coord= (const float*)d_in[7];
  float* out = (float*)d_out;

  char* ws = (char*)d_ws;
  bf16* z   = (bf16*)(ws + 0);                 //  84,934,656 B  [kc][41472 row'][32]
  bf16* PTt = (bf16*)(ws + 84934656);          //   4,194,304 B  [kc][2048][32]
  bf16* mmb = (bf16*)(ws + 89128960);          //   4,718,592 B
  bf16* UT  = (bf16*)(ws + 93847552);          //   2,097,152 B  [512][2048]
  bf16* VT  = (bf16*)(ws + 95944704);          //   2,097,152 B
  float* uf = (float*)(ws + 98041856);         //   2,359,296 B
  float* vf = (float*)(ws + 100401152);
  float* uc = (float*)(ws + 102760448);
  float* vc = (float*)(ws + 105119744);
  float* uf2= (float*)(ws + 107479040);
  float* vf2= (float*)(ws + 109838336);        // end 112,197,632

  k_prep<<<dim3(7552), dim3(256), 0, stream>>>(mm, coords, U_feat, V_feat, P_feat,
                                               U_coord, V_coord, P_coord,
                                               mmb, UT, VT, PTt, uc, vc);
  k_gemm_uv<<<dim3(18, 4, 4), dim3(256), 0, stream>>>(mmb, UT, VT, uf, vf, uf2, vf2);
  k_build_z<<<dim3(8, 32, 2), dim3(256), 0, stream>>>(uc, vc, uf, vf, uf2, vf2, z);
  k_main<<<dim3(2304), dim3(256), 0, stream>>>(z, PTt, mm, out);
}